// Round 18
// baseline (115.311 us; speedup 1.0000x reference)
//
#include <hip/hip_runtime.h>
#include <hip/hip_bf16.h>

typedef short bf16x8 __attribute__((ext_vector_type(8)));
typedef float f32x4  __attribute__((ext_vector_type(4)));
typedef float f32x16 __attribute__((ext_vector_type(16)));

union fragU { f32x4 f; bf16x8 b; uint4 q; uint u[4]; };

// RNE f32->bf16 (pre-kernels only)
__device__ inline ushort f2bf(float f) {
    union { float f; uint u; } v; v.f = f;
    uint r = (v.u + 0x7FFFu + ((v.u >> 16) & 1u)) >> 16;
    return (ushort)r;
}
__device__ inline uint packbf(float a, float b) {
    return (uint)f2bf(a) | ((uint)f2bf(b) << 16);
}
// hot path: single-instruction RNE pack
__device__ inline uint cvtpk(float lo, float hi) {
    uint r;
    asm("v_cvt_pk_bf16_f32 %0, %1, %2" : "=v"(r) : "v"(lo), "v"(hi));
    return r;
}

// ---- pre-kernel A: pack x rows: [f0..f4, 1.0, 0, 0] bf16 ----
__global__ __launch_bounds__(256) void pack_x_kernel(
    const float* __restrict__ x, uint4* __restrict__ xp, int N)
{
    int i = blockIdx.x * blockDim.x + threadIdx.x;
    if (i >= N) return;
    const float* r = x + (size_t)i * 5;
    uint4 o;
    o.x = packbf(r[0], r[1]);
    o.y = packbf(r[2], r[3]);
    o.z = packbf(r[4], 1.0f);    // slot 5 = 1.0 : bias enabler
    o.w = 0u;
    xp[i] = o;
}

// ---- pre-kernel B: per-lane fragment table for 32x32x16 layout (as R16) ----
__global__ __launch_bounds__(64) void pack_w_kernel(
    const float* __restrict__ W1, const float* __restrict__ b1,
    const float* __restrict__ W2, const float* __restrict__ b2,
    const float* __restrict__ W3, uint4* __restrict__ tab)
{
    const int lane = threadIdx.x;       // one wave
    const int col  = lane & 31;
    const int hi   = lane >> 5;

    union { ushort s[8]; uint4 q; } u;
    #pragma unroll
    for (int T = 0; T < 2; ++T) {
        #pragma unroll
        for (int d = 0; d < 8; ++d) {
            int k = 8 * hi + d;
            int j = 32 * T + col;
            float v = 0.f;
            if (j < 50) {
                if (k < 5)                 v = W1[k * 50 + j];
                else if (k == 5)           v = b1[j];
                else if (k >= 8 && k < 13) v = W1[(k - 3) * 50 + j];
            } else if (j == 50 && k == 5)  v = 1.0f;
            u.s[d] = f2bf(v);
        }
        tab[T * 64 + lane] = u.q;
    }
    #pragma unroll
    for (int T = 0; T < 2; ++T) {
        #pragma unroll
        for (int s = 0; s < 4; ++s) {
            #pragma unroll
            for (int d = 0; d < 8; ++d) {
                int kg = 16 * s + 8 * hi + d;
                int j  = 32 * T + col;
                float v = 0.f;
                if (j < 50) {
                    if (kg < 50)       v = W2[kg * 50 + j];
                    else if (kg == 50) v = b2[j];
                }
                u.s[d] = f2bf(v);
            }
            tab[(2 + T * 4 + s) * 64 + lane] = u.q;
        }
    }
    #pragma unroll
    for (int s = 0; s < 4; ++s) {
        #pragma unroll
        for (int d = 0; d < 8; ++d) {
            int kg = 16 * s + 8 * hi + d;
            float v = (col == 0 && kg < 50) ? W3[kg] : 0.f;
            u.s[d] = f2bf(v);
        }
        tab[(10 + s) * 64 + lane] = u.q;
    }
}

// ---- phase G: pure gather at max occupancy. EFp[e] = {xp[src], xp[tgt]} ----
// (tgt half's 1.0 at k=13 is harmless: W1ext row 13 is zero.)
__global__ __launch_bounds__(256) void build_ef_kernel(
    const uint4* __restrict__ xp, const int* __restrict__ ei,
    uint4* __restrict__ efp, int E)
{
    int e = blockIdx.x * blockDim.x + threadIdx.x;
    if (e >= E) return;
    int s = __builtin_nontemporal_load(&ei[e]);
    int t = __builtin_nontemporal_load(&ei[E + e]);
    uint4 qs = xp[s];
    uint4 qt = xp[t];
    efp[2 * (size_t)e]     = qs;
    efp[2 * (size_t)e + 1] = qt;
}

// ---- phase C: pure streaming compute, zero scatter. 32 edges/wave-job. ----
__global__ __launch_bounds__(256, 3) void edge_mlp_stream(
    const uint4* __restrict__ efp,
    const uint4* __restrict__ wtab,
    const float* __restrict__ b3,
    float* __restrict__ out, int E, int NT)
{
    const int tid  = threadIdx.x;
    const int w    = tid >> 6;
    const int lane = tid & 63;
    const int col  = lane & 31;
    const int hi   = lane >> 5;
    const int G    = gridDim.x;

    fragU w1f[2], w2f[8], w3a[4];
    #pragma unroll
    for (int i = 0; i < 2; ++i) w1f[i].q = wtab[i * 64 + lane];
    #pragma unroll
    for (int i = 0; i < 8; ++i) w2f[i].q = wtab[(2 + i) * 64 + lane];
    #pragma unroll
    for (int i = 0; i < 4; ++i) w3a[i].q = wtab[(10 + i) * 64 + lane];
    asm volatile("" :
        "+v"(w1f[0].f), "+v"(w1f[1].f),
        "+v"(w2f[0].f), "+v"(w2f[1].f), "+v"(w2f[2].f), "+v"(w2f[3].f),
        "+v"(w2f[4].f), "+v"(w2f[5].f), "+v"(w2f[6].f), "+v"(w2f[7].f),
        "+v"(w3a[0].f), "+v"(w3a[1].f), "+v"(w3a[2].f), "+v"(w3a[3].f));

    const float b3s = b3[0];

    const f32x16 z16 = {0.f,0.f,0.f,0.f, 0.f,0.f,0.f,0.f,
                        0.f,0.f,0.f,0.f, 0.f,0.f,0.f,0.f};

    // coalesced EF row load: lane (col,hi) -> efp[2*(tile edge)+hi], 1KB/wave
    auto LOADF = [&](int t_) -> fragU {
        int tc = (t_ < NT) ? t_ : (NT - 1);
        int e = tc * 128 + w * 32 + col;
        if (e >= E) e = E - 1;
        fragU a; a.q = efp[2 * (size_t)e + (size_t)hi];
        return a;
    };

    auto INTERFACE = [&](const f32x16& c0, const f32x16& c1, fragU* bf) {
        uint word[2][8];
        #pragma unroll
        for (int k = 0; k < 8; ++k) {
            word[0][k] = cvtpk(fmaxf(c0[2*k], 0.f), fmaxf(c0[2*k+1], 0.f));
            word[1][k] = cvtpk(fmaxf(c1[2*k], 0.f), fmaxf(c1[2*k+1], 0.f));
        }
        #pragma unroll
        for (int s = 0; s < 4; ++s) {
            #pragma unroll
            for (int n = 0; n < 2; ++n) {
                const int mD = 2 * s, mS = 2 * s + 1;
                uint D = word[mD >> 2][2 * (mD & 3) + n];
                uint S = word[mS >> 2][2 * (mS & 3) + n];
                asm volatile("v_permlane32_swap_b32 %0, %1" : "+v"(D), "+v"(S));
                bf[s].u[n]     = D;
                bf[s].u[2 + n] = S;
            }
        }
    };

    int t = blockIdx.x;
    if (t >= NT) return;

    fragU f0 = LOADF(t);

    for (; t < NT; t += G) {
        fragU f1 = LOADF(t + G);          // streaming prefetch, 1 tile ahead

        f32x16 c1_0 = __builtin_amdgcn_mfma_f32_32x32x16_bf16(w1f[0].b, f0.b, z16, 0, 0, 0);
        f32x16 c1_1 = __builtin_amdgcn_mfma_f32_32x32x16_bf16(w1f[1].b, f0.b, z16, 0, 0, 0);

        fragU bf[4];
        INTERFACE(c1_0, c1_1, bf);

        f32x16 c2_0 = z16, c2_1 = z16;
        #pragma unroll
        for (int s = 0; s < 4; ++s) {
            c2_0 = __builtin_amdgcn_mfma_f32_32x32x16_bf16(w2f[s].b,     bf[s].b, c2_0, 0, 0, 0);
            c2_1 = __builtin_amdgcn_mfma_f32_32x32x16_bf16(w2f[4 + s].b, bf[s].b, c2_1, 0, 0, 0);
        }

        fragU bf2[4];
        INTERFACE(c2_0, c2_1, bf2);

        f32x16 c3 = z16;
        #pragma unroll
        for (int s = 0; s < 4; ++s)
            c3 = __builtin_amdgcn_mfma_f32_32x32x16_bf16(w3a[s].b, bf2[s].b, c3, 0, 0, 0);

        if (hi == 0) {
            int e = t * 128 + w * 32 + col;
            if (e < E) {
                float ex = __expf(-(c3[0] + b3s));
                out[e] = __builtin_amdgcn_rcpf(1.f + ex);
            }
        }

        f0 = f1;
    }
}

// ---- fallback: R16 fused kernel (used only if ws_size is too small) ----
__global__ __launch_bounds__(256, 4) void edge_mlp_fused(
    const uint4* __restrict__ xp,
    const uint4* __restrict__ wtab,
    const int* __restrict__ ei,
    const float* __restrict__ b3,
    float* __restrict__ out, int E, int NT)
{
    const int tid  = threadIdx.x;
    const int w    = tid >> 6;
    const int lane = tid & 63;
    const int col  = lane & 31;
    const int hi   = lane >> 5;
    const int G    = gridDim.x;

    fragU w1f[2], w2f[8], w3a[4];
    #pragma unroll
    for (int i = 0; i < 2; ++i) w1f[i].q = wtab[i * 64 + lane];
    #pragma unroll
    for (int i = 0; i < 8; ++i) w2f[i].q = wtab[(2 + i) * 64 + lane];
    #pragma unroll
    for (int i = 0; i < 4; ++i) w3a[i].q = wtab[(10 + i) * 64 + lane];
    asm volatile("" :
        "+v"(w1f[0].f), "+v"(w1f[1].f),
        "+v"(w2f[0].f), "+v"(w2f[1].f), "+v"(w2f[2].f), "+v"(w2f[3].f),
        "+v"(w2f[4].f), "+v"(w2f[5].f), "+v"(w2f[6].f), "+v"(w2f[7].f),
        "+v"(w3a[0].f), "+v"(w3a[1].f), "+v"(w3a[2].f), "+v"(w3a[3].f));

    const float b3s = b3[0];

    auto LOAD_IDX = [&](int t_) -> int {
        int tc = (t_ < NT) ? t_ : (NT - 1);
        int e = tc * 128 + w * 32 + col;
        if (e >= E) e = 0;
        return ei[(size_t)hi * (size_t)E + (size_t)e];
    };

    const f32x16 z16 = {0.f,0.f,0.f,0.f, 0.f,0.f,0.f,0.f,
                        0.f,0.f,0.f,0.f, 0.f,0.f,0.f,0.f};

    auto INTERFACE = [&](const f32x16& c0, const f32x16& c1, fragU* bf) {
        uint word[2][8];
        #pragma unroll
        for (int k = 0; k < 8; ++k) {
            word[0][k] = cvtpk(fmaxf(c0[2*k], 0.f), fmaxf(c0[2*k+1], 0.f));
            word[1][k] = cvtpk(fmaxf(c1[2*k], 0.f), fmaxf(c1[2*k+1], 0.f));
        }
        #pragma unroll
        for (int s = 0; s < 4; ++s) {
            #pragma unroll
            for (int n = 0; n < 2; ++n) {
                const int mD = 2 * s, mS = 2 * s + 1;
                uint D = word[mD >> 2][2 * (mD & 3) + n];
                uint S = word[mS >> 2][2 * (mS & 3) + n];
                asm volatile("v_permlane32_swap_b32 %0, %1" : "+v"(D), "+v"(S));
                bf[s].u[n]     = D;
                bf[s].u[2 + n] = S;
            }
        }
    };

    int t = blockIdx.x;
    if (t >= NT) return;

    fragU f0; f0.q = xp[LOAD_IDX(t)];
    int idx1 = LOAD_IDX(t + G);

    for (; t < NT; t += G) {
        fragU f1; f1.q = xp[idx1];
        idx1 = LOAD_IDX(t + 2 * G);

        f32x16 c1_0 = __builtin_amdgcn_mfma_f32_32x32x16_bf16(w1f[0].b, f0.b, z16, 0, 0, 0);
        f32x16 c1_1 = __builtin_amdgcn_mfma_f32_32x32x16_bf16(w1f[1].b, f0.b, z16, 0, 0, 0);

        fragU bf[4];
        INTERFACE(c1_0, c1_1, bf);

        f32x16 c2_0 = z16, c2_1 = z16;
        #pragma unroll
        for (int s = 0; s < 4; ++s) {
            c2_0 = __builtin_amdgcn_mfma_f32_32x32x16_bf16(w2f[s].b,     bf[s].b, c2_0, 0, 0, 0);
            c2_1 = __builtin_amdgcn_mfma_f32_32x32x16_bf16(w2f[4 + s].b, bf[s].b, c2_1, 0, 0, 0);
        }

        fragU bf2[4];
        INTERFACE(c2_0, c2_1, bf2);

        f32x16 c3 = z16;
        #pragma unroll
        for (int s = 0; s < 4; ++s)
            c3 = __builtin_amdgcn_mfma_f32_32x32x16_bf16(w3a[s].b, bf2[s].b, c3, 0, 0, 0);

        if (hi == 0) {
            int e = t * 128 + w * 32 + col;
            if (e < E) {
                float ex = __expf(-(c3[0] + b3s));
                out[e] = __builtin_amdgcn_rcpf(1.f + ex);
            }
        }

        f0 = f1;
    }
}

extern "C" void kernel_launch(void* const* d_in, const int* in_sizes, int n_in,
                              void* d_out, int out_size, void* d_ws, size_t ws_size,
                              hipStream_t stream) {
    const float* x  = (const float*)d_in[0];
    const int*   ei = (const int*)d_in[1];
    const float* W1 = (const float*)d_in[2];
    const float* b1 = (const float*)d_in[3];
    const float* W2 = (const float*)d_in[4];
    const float* b2 = (const float*)d_in[5];
    const float* W3 = (const float*)d_in[6];
    const float* b3 = (const float*)d_in[7];
    float* out = (float*)d_out;

    int E = in_sizes[1] / 2;      // edge_index is [2, E]
    int N = in_sizes[0] / 5;      // nodes

    const size_t XP_OFF  = 32768;                  // 14KB wtab, pad to 32KB
    const size_t EFP_OFF = (size_t)4 << 20;        // xp < 4MB-32KB for N=100K
    const size_t needed  = EFP_OFF + (size_t)E * 32;

    uint4* wtab = (uint4*)d_ws;
    uint4* xp   = (uint4*)((char*)d_ws + XP_OFF);

    pack_w_kernel<<<1, 64, 0, stream>>>(W1, b1, W2, b2, W3, wtab);
    pack_x_kernel<<<(N + 255) / 256, 256, 0, stream>>>(x, xp, N);

    int NT = (E + 127) / 128;
    int grid = NT < 2048 ? NT : 2048;

    if (ws_size >= needed) {
        uint4* efp = (uint4*)((char*)d_ws + EFP_OFF);
        build_ef_kernel<<<(E + 255) / 256, 256, 0, stream>>>(xp, ei, efp, E);
        edge_mlp_stream<<<grid, 256, 0, stream>>>(efp, wtab, b3, out, E, NT);
    } else {
        edge_mlp_fused<<<grid, 256, 0, stream>>>(xp, wtab, ei, b3, out, E, NT);
    }
}

// Round 19
// 65.397 us; speedup vs baseline: 1.7632x; 1.7632x over previous
//
#include <hip/hip_runtime.h>
#include <hip/hip_bf16.h>

typedef short bf16x8 __attribute__((ext_vector_type(8)));
typedef float f32x4  __attribute__((ext_vector_type(4)));
typedef float f32x16 __attribute__((ext_vector_type(16)));

union fragU { f32x4 f; bf16x8 b; uint4 q; uint u[4]; };

// RNE f32->bf16 (pre-kernels only)
__device__ inline ushort f2bf(float f) {
    union { float f; uint u; } v; v.f = f;
    uint r = (v.u + 0x7FFFu + ((v.u >> 16) & 1u)) >> 16;
    return (ushort)r;
}
__device__ inline uint packbf(float a, float b) {
    return (uint)f2bf(a) | ((uint)f2bf(b) << 16);
}
// hot path: single-instruction RNE pack
__device__ inline uint cvtpk(float lo, float hi) {
    uint r;
    asm("v_cvt_pk_bf16_f32 %0, %1, %2" : "=v"(r) : "v"(lo), "v"(hi));
    return r;
}

// ---- pre-kernel A: pack x rows: [f0..f4, 1.0, 0, 0] bf16 ----
__global__ __launch_bounds__(256) void pack_x_kernel(
    const float* __restrict__ x, uint4* __restrict__ xp, int N)
{
    int i = blockIdx.x * blockDim.x + threadIdx.x;
    if (i >= N) return;
    const float* r = x + (size_t)i * 5;
    uint4 o;
    o.x = packbf(r[0], r[1]);
    o.y = packbf(r[2], r[3]);
    o.z = packbf(r[4], 1.0f);    // slot 5 = 1.0 : bias enabler
    o.w = 0u;                    // slots 6,7 = 0
    xp[i] = o;
}

// ---- pre-kernel B: per-lane fragment table for 32x32x16 layout ----
// A-frag (32x32x16): row = lane&31, k = 8*(lane>>5)+d.  C: col=lane&31,
// row = (reg&3)+8*(reg>>2)+4*(lane>>5) (+32*T for row-tile T).
// chunk 0..1  : W1ext^T A-frags, tile T (EF k-layout: 0..4 src, 5=1.0->b1,
//               8..12 tgt, rest 0; j==50,k==5 -> 1.0 enabler for b2)
// chunk 2..9  : W2ext^T A-frags [T][s], kg=16s+8hi+d; kg==50 -> b2
// chunk 10..13: W3 A-frags, slice s (row 0 only): col==0 -> W3[kg], else 0
__global__ __launch_bounds__(64) void pack_w_kernel(
    const float* __restrict__ W1, const float* __restrict__ b1,
    const float* __restrict__ W2, const float* __restrict__ b2,
    const float* __restrict__ W3, uint4* __restrict__ tab)
{
    const int lane = threadIdx.x;       // one wave
    const int col  = lane & 31;
    const int hi   = lane >> 5;

    union { ushort s[8]; uint4 q; } u;
    #pragma unroll
    for (int T = 0; T < 2; ++T) {
        #pragma unroll
        for (int d = 0; d < 8; ++d) {
            int k = 8 * hi + d;
            int j = 32 * T + col;
            float v = 0.f;
            if (j < 50) {
                if (k < 5)                 v = W1[k * 50 + j];
                else if (k == 5)           v = b1[j];
                else if (k >= 8 && k < 13) v = W1[(k - 3) * 50 + j];
            } else if (j == 50 && k == 5)  v = 1.0f;
            u.s[d] = f2bf(v);
        }
        tab[T * 64 + lane] = u.q;
    }
    #pragma unroll
    for (int T = 0; T < 2; ++T) {
        #pragma unroll
        for (int s = 0; s < 4; ++s) {
            #pragma unroll
            for (int d = 0; d < 8; ++d) {
                int kg = 16 * s + 8 * hi + d;
                int j  = 32 * T + col;
                float v = 0.f;
                if (j < 50) {
                    if (kg < 50)       v = W2[kg * 50 + j];
                    else if (kg == 50) v = b2[j];
                }
                u.s[d] = f2bf(v);
            }
            tab[(2 + T * 4 + s) * 64 + lane] = u.q;
        }
    }
    #pragma unroll
    for (int s = 0; s < 4; ++s) {
        #pragma unroll
        for (int d = 0; d < 8; ++d) {
            int kg = 16 * s + 8 * hi + d;
            float v = (col == 0 && kg < 50) ? W3[kg] : 0.f;
            u.s[d] = f2bf(v);
        }
        tab[(10 + s) * 64 + lane] = u.q;
    }
}

// ---- main: R16 body verbatim; ONLY change: launch_bounds (256,4)->(256,2)
//      (occupancy proven irrelevant 25<->32%; give regalloc the full file) ----
__global__ __launch_bounds__(256, 2) void edge_mlp_mfma15(
    const uint4* __restrict__ xp,
    const uint4* __restrict__ wtab,
    const int* __restrict__ ei,
    const float* __restrict__ b3,
    float* __restrict__ out, int E, int NT)
{
    const int tid  = threadIdx.x;
    const int w    = tid >> 6;
    const int lane = tid & 63;
    const int col  = lane & 31;
    const int hi   = lane >> 5;
    const int G    = gridDim.x;

    // one-time coalesced fragment load, then PIN in registers (14 fragU = 56)
    fragU w1f[2], w2f[8], w3a[4];
    #pragma unroll
    for (int i = 0; i < 2; ++i) w1f[i].q = wtab[i * 64 + lane];
    #pragma unroll
    for (int i = 0; i < 8; ++i) w2f[i].q = wtab[(2 + i) * 64 + lane];
    #pragma unroll
    for (int i = 0; i < 4; ++i) w3a[i].q = wtab[(10 + i) * 64 + lane];
    asm volatile("" :
        "+v"(w1f[0].f), "+v"(w1f[1].f),
        "+v"(w2f[0].f), "+v"(w2f[1].f), "+v"(w2f[2].f), "+v"(w2f[3].f),
        "+v"(w2f[4].f), "+v"(w2f[5].f), "+v"(w2f[6].f), "+v"(w2f[7].f),
        "+v"(w3a[0].f), "+v"(w3a[1].f), "+v"(w3a[2].f), "+v"(w3a[3].f));

    const float b3s = b3[0];

    // index for tile t: lane (col, hi) -> ei[hi*E + t*128 + w*32 + col]
    auto LOAD_IDX = [&](int t_) -> int {
        int tc = (t_ < NT) ? t_ : (NT - 1);
        int e = tc * 128 + w * 32 + col;
        if (e >= E) e = 0;
        return ei[(size_t)hi * (size_t)E + (size_t)e];
    };

    const f32x16 z16 = {0.f,0.f,0.f,0.f, 0.f,0.f,0.f,0.f,
                        0.f,0.f,0.f,0.f, 0.f,0.f,0.f,0.f};

    // relu + pack + permlane32_swap: C-frag pair -> 4 B-frags, k=16s+8hi+d
    auto INTERFACE = [&](const f32x16& c0, const f32x16& c1, fragU* bf) {
        uint word[2][8];
        #pragma unroll
        for (int k = 0; k < 8; ++k) {
            word[0][k] = cvtpk(fmaxf(c0[2*k], 0.f), fmaxf(c0[2*k+1], 0.f));
            word[1][k] = cvtpk(fmaxf(c1[2*k], 0.f), fmaxf(c1[2*k+1], 0.f));
        }
        #pragma unroll
        for (int s = 0; s < 4; ++s) {
            #pragma unroll
            for (int n = 0; n < 2; ++n) {
                const int mD = 2 * s, mS = 2 * s + 1;
                uint D = word[mD >> 2][2 * (mD & 3) + n];
                uint S = word[mS >> 2][2 * (mS & 3) + n];
                asm volatile("v_permlane32_swap_b32 %0, %1" : "+v"(D), "+v"(S));
                bf[s].u[n]     = D;
                bf[s].u[2 + n] = S;
            }
        }
    };

    int t = blockIdx.x;
    if (t >= NT) return;

    // 2-deep decoupled pipeline prologue
    fragU f0; f0.q = xp[LOAD_IDX(t)];
    int idx1 = LOAD_IDX(t + G);

    for (; t < NT; t += G) {
        fragU f1; f1.q = xp[idx1];      // gather for t+G (resident address)
        idx1 = LOAD_IDX(t + 2 * G);     // idx for t+2G (independent)

        // ---- layer 1 (+b1 folded): 2 row-tiles ----
        f32x16 c1_0 = __builtin_amdgcn_mfma_f32_32x32x16_bf16(w1f[0].b, f0.b, z16, 0, 0, 0);
        f32x16 c1_1 = __builtin_amdgcn_mfma_f32_32x32x16_bf16(w1f[1].b, f0.b, z16, 0, 0, 0);

        // ---- interface 1: h1 C-frags -> layer-2 B-frags ----
        fragU bf[4];
        INTERFACE(c1_0, c1_1, bf);

        // ---- layer 2 (+b2 folded): 2 row-tiles x 4 K-slices ----
        f32x16 c2_0 = z16, c2_1 = z16;
        #pragma unroll
        for (int s = 0; s < 4; ++s) {
            c2_0 = __builtin_amdgcn_mfma_f32_32x32x16_bf16(w2f[s].b,     bf[s].b, c2_0, 0, 0, 0);
            c2_1 = __builtin_amdgcn_mfma_f32_32x32x16_bf16(w2f[4 + s].b, bf[s].b, c2_1, 0, 0, 0);
        }

        // ---- interface 2: h2 C-frags -> layer-3 B-frags (same transform) ----
        fragU bf2[4];
        INTERFACE(c2_0, c2_1, bf2);

        // ---- layer 3: 4 MFMAs, W3 in A row 0; result in C row 0 ----
        f32x16 c3 = z16;
        #pragma unroll
        for (int s = 0; s < 4; ++s)
            c3 = __builtin_amdgcn_mfma_f32_32x32x16_bf16(w3a[s].b, bf2[s].b, c3, 0, 0, 0);

        if (hi == 0) {                    // C row 0 -> reg 0, lanes 0..31
            int e = t * 128 + w * 32 + col;
            if (e < E) {
                float ex = __expf(-(c3[0] + b3s));
                out[e] = __builtin_amdgcn_rcpf(1.f + ex);
            }
        }

        f0 = f1;
    }
}

extern "C" void kernel_launch(void* const* d_in, const int* in_sizes, int n_in,
                              void* d_out, int out_size, void* d_ws, size_t ws_size,
                              hipStream_t stream) {
    const float* x  = (const float*)d_in[0];
    const int*   ei = (const int*)d_in[1];
    const float* W1 = (const float*)d_in[2];
    const float* b1 = (const float*)d_in[3];
    const float* W2 = (const float*)d_in[4];
    const float* b2 = (const float*)d_in[5];
    const float* W3 = (const float*)d_in[6];
    const float* b3 = (const float*)d_in[7];
    float* out = (float*)d_out;

    int E = in_sizes[1] / 2;      // edge_index is [2, E]
    int N = in_sizes[0] / 5;      // nodes

    uint4* wtab = (uint4*)d_ws;                    // 14 KB fragment table
    uint4* xp   = (uint4*)((char*)d_ws + 32768);   // N * 16 B packed x

    pack_w_kernel<<<1, 64, 0, stream>>>(W1, b1, W2, b2, W3, wtab);
    pack_x_kernel<<<(N + 255) / 256, 256, 0, stream>>>(x, xp, N);

    int NT = (E + 127) / 128;                      // 128 edges per block-tile
    int grid = NT < 2048 ? NT : 2048;
    edge_mlp_mfma15<<<grid, 256, 0, stream>>>(xp, wtab, ei, b3, out, E, NT);
}